// Round 3
// baseline (1363.052 us; speedup 1.0000x reference)
//
#include <hip/hip_runtime.h>
#include <hip/hip_bf16.h>
#include <math.h>

#define B_ 256
#define T_ 240
#define N_ 264
#define H_ 256
#define BN_ (B_ * N_)
#define PHI_ 0.94247778f   // 3.1415926 * 0.3
#define MAXNORM_ 0.996f    // (1 - 4e-3)/sqrt(c), c=1

// ---------------------------------------------------------------------------
// Kernel 1: per-(b,n) mean and 1/std over T (single pass)
// ---------------------------------------------------------------------------
__global__ __launch_bounds__(256) void stats_kernel(
    const float* __restrict__ data, float* __restrict__ mean, float* __restrict__ rd) {
  int b = blockIdx.x;
  const float* db = data + (size_t)b * T_ * N_;
  for (int n = threadIdx.x; n < N_; n += blockDim.x) {
    float s = 0.f, ss = 0.f;
    for (int t = 0; t < T_; ++t) {
      float v = db[(size_t)t * N_ + n];
      s += v; ss += v * v;
    }
    float m = s / (float)T_;
    float var = ss - s * m;           // = ss - s^2/T = sum((x-m)^2)
    float d = sqrtf(fmaxf(var, 0.f));
    mean[b * N_ + n] = m;
    rd[b * N_ + n] = (d > 0.f) ? (1.f / d) : 0.f;   // nan_to_num semantics
  }
}

// ---------------------------------------------------------------------------
// Kernel 2: adj[b,i,j] = | cov_ij * rd_i * rd_j |, cov = xm^T xm (K = T_)
// 64x64 tile per block, 256 threads, 4x4 micro-tile
// ---------------------------------------------------------------------------
__global__ __launch_bounds__(256) void corr_kernel(
    const float* __restrict__ data, const float* __restrict__ mean,
    const float* __restrict__ rd, float* __restrict__ adj) {
  int b  = blockIdx.z;
  int i0 = blockIdx.y * 64, j0 = blockIdx.x * 64;
  __shared__ float As[16][64];
  __shared__ float Bs[16][64];
  int tid = threadIdx.x;
  int tx = tid % 16, ty = tid / 16;
  float acc[4][4] = {};
  const float* db = data + (size_t)b * T_ * N_;
  const float* mb = mean + b * N_;

  for (int k0 = 0; k0 < T_; k0 += 16) {
    for (int it = 0; it < 4; ++it) {
      int t = (tid >> 6) + it * 4;       // 0..15
      int col = tid & 63;
      int gt = k0 + t;
      int gi = i0 + col, gj = j0 + col;
      As[t][col] = (gi < N_) ? (db[(size_t)gt * N_ + gi] - mb[gi]) : 0.f;
      Bs[t][col] = (gj < N_) ? (db[(size_t)gt * N_ + gj] - mb[gj]) : 0.f;
    }
    __syncthreads();
#pragma unroll
    for (int t = 0; t < 16; ++t) {
      float a[4], bb[4];
#pragma unroll
      for (int u = 0; u < 4; ++u) a[u]  = As[t][ty * 4 + u];
#pragma unroll
      for (int u = 0; u < 4; ++u) bb[u] = Bs[t][tx * 4 + u];
#pragma unroll
      for (int u = 0; u < 4; ++u)
#pragma unroll
        for (int v = 0; v < 4; ++v) acc[u][v] += a[u] * bb[v];
    }
    __syncthreads();
  }

  const float* rdb = rd + b * N_;
#pragma unroll
  for (int u = 0; u < 4; ++u) {
    int i = i0 + ty * 4 + u;
    if (i >= N_) continue;
    float ri = rdb[i];
#pragma unroll
    for (int v = 0; v < 4; ++v) {
      int j = j0 + tx * 4 + v;
      if (j >= N_) continue;
      adj[((size_t)b * N_ + i) * N_ + j] = fabsf(acc[u][v] * ri * rdb[j]);
    }
  }
}

// ---------------------------------------------------------------------------
// Kernel 3: dinv[b,i] = (sum_j adj[b,i,j] + 1)^-1/2    (one wave per row)
// ---------------------------------------------------------------------------
__global__ __launch_bounds__(256) void dinv_kernel(
    const float* __restrict__ adj, float* __restrict__ dinv) {
  int row  = blockIdx.x * 4 + (threadIdx.x >> 6);   // b*N_+i
  int lane = threadIdx.x & 63;
  const float* r = adj + (size_t)row * N_;
  float s = 0.f;
  for (int j = lane; j < N_; j += 64) s += r[j];
#pragma unroll
  for (int off = 32; off; off >>= 1) s += __shfl_down(s, off);
  if (lane == 0) dinv[row] = 1.f / sqrtf(s + 1.f);
}

// ---------------------------------------------------------------------------
// Kernel 4: Y[b,:,:] = A[b] @ W   (A: [B, 264, K] batched, W: [K, 256] shared)
// ---------------------------------------------------------------------------
template <int K>
__global__ __launch_bounds__(256) void gemm_aw_kernel(
    const float* __restrict__ A, const float* __restrict__ W, float* __restrict__ Y) {
  int b  = blockIdx.z;
  int i0 = blockIdx.y * 64, h0 = blockIdx.x * 64;
  __shared__ float As[64][17];
  __shared__ float Ws[16][64];
  int tid = threadIdx.x;
  int tx = tid % 16, ty = tid / 16;
  float acc[4][4] = {};
  const float* Ab = A + (size_t)b * N_ * K;

  for (int k0 = 0; k0 < K; k0 += 16) {
    {
      int il = tid >> 2, kq = (tid & 3) * 4;
      int gi = i0 + il;
#pragma unroll
      for (int u = 0; u < 4; ++u) {
        int gk = k0 + kq + u;
        As[il][kq + u] = (gi < N_ && gk < K) ? Ab[(size_t)gi * K + gk] : 0.f;
      }
    }
#pragma unroll
    for (int it = 0; it < 4; ++it) {
      int kk = (tid >> 6) + it * 4, h = tid & 63;
      int gk = k0 + kk;
      Ws[kk][h] = (gk < K) ? W[(size_t)gk * H_ + h0 + h] : 0.f;
    }
    __syncthreads();
#pragma unroll
    for (int k = 0; k < 16; ++k) {
      float a[4], w[4];
#pragma unroll
      for (int u = 0; u < 4; ++u) a[u] = As[ty * 4 + u][k];
#pragma unroll
      for (int u = 0; u < 4; ++u) w[u] = Ws[k][tx * 4 + u];
#pragma unroll
      for (int u = 0; u < 4; ++u)
#pragma unroll
        for (int v = 0; v < 4; ++v) acc[u][v] += a[u] * w[v];
    }
    __syncthreads();
  }
#pragma unroll
  for (int u = 0; u < 4; ++u) {
    int i = i0 + ty * 4 + u;
    if (i >= N_) continue;
#pragma unroll
    for (int v = 0; v < 4; ++v) {
      int h = h0 + tx * 4 + v;
      Y[((size_t)b * N_ + i) * H_ + h] = acc[u][v];
    }
  }
}

// ---------------------------------------------------------------------------
// Kernel 5: X[b,i,h] = dinv_i*( sum_j adj[b,i,j]*dinv_j*Y[b,j,h] + dinv_i*Y[b,i,h] ) + bias[h]
// (this is L @ Y + bias with L = D^-1/2 (adj+I) D^-1/2, L never materialized)
// ---------------------------------------------------------------------------
__global__ __launch_bounds__(256) void gemm_lx_kernel(
    const float* __restrict__ adj, const float* __restrict__ dinv,
    const float* __restrict__ Y, const float* __restrict__ bias,
    float* __restrict__ X) {
  int b  = blockIdx.z;
  int i0 = blockIdx.y * 64, h0 = blockIdx.x * 64;
  __shared__ float As[64][17];
  __shared__ float Ys[16][64];
  int tid = threadIdx.x;
  int tx = tid % 16, ty = tid / 16;
  float acc[4][4] = {};
  const float* Ab = adj + (size_t)b * N_ * N_;
  const float* db = dinv + b * N_;

  for (int k0 = 0; k0 < N_; k0 += 16) {
    {
      int il = tid >> 2, kq = (tid & 3) * 4;
      int gi = i0 + il;
#pragma unroll
      for (int u = 0; u < 4; ++u) {
        int gj = k0 + kq + u;
        As[il][kq + u] = (gi < N_ && gj < N_) ? Ab[(size_t)gi * N_ + gj] : 0.f;
      }
    }
#pragma unroll
    for (int it = 0; it < 4; ++it) {
      int kk = (tid >> 6) + it * 4, h = tid & 63;
      int gj = k0 + kk;
      Ys[kk][h] = (gj < N_) ? db[gj] * Y[((size_t)b * N_ + gj) * H_ + h0 + h] : 0.f;
    }
    __syncthreads();
#pragma unroll
    for (int k = 0; k < 16; ++k) {
      float a[4], w[4];
#pragma unroll
      for (int u = 0; u < 4; ++u) a[u] = As[ty * 4 + u][k];
#pragma unroll
      for (int u = 0; u < 4; ++u) w[u] = Ys[k][tx * 4 + u];
#pragma unroll
      for (int u = 0; u < 4; ++u)
#pragma unroll
        for (int v = 0; v < 4; ++v) acc[u][v] += a[u] * w[v];
    }
    __syncthreads();
  }
#pragma unroll
  for (int u = 0; u < 4; ++u) {
    int i = i0 + ty * 4 + u;
    if (i >= N_) continue;
    float di = db[i];
#pragma unroll
    for (int v = 0; v < 4; ++v) {
      int h = h0 + tx * 4 + v;
      float yi = Y[((size_t)b * N_ + i) * H_ + h];
      X[((size_t)b * N_ + i) * H_ + h] = di * (acc[u][v] + di * yi) + bias[h];
    }
  }
}

// ---------------------------------------------------------------------------
// Kernel 6: G = act(fkernel(X))  per row (b,i) of H_=256 elements
// fkernel = logmap0(project(x,1),1); act(y) = relu(y) + 0.5*cos(y+PHI)
// ---------------------------------------------------------------------------
__global__ __launch_bounds__(256) void actfk_kernel(
    const float* __restrict__ X, float* __restrict__ G) {
  size_t row = blockIdx.x;            // b*N_+i
  float x = X[row * H_ + threadIdx.x];
  float ss = x * x;
#pragma unroll
  for (int off = 32; off; off >>= 1) ss += __shfl_down(ss, off);
  __shared__ float wsum[4];
  if ((threadIdx.x & 63) == 0) wsum[threadIdx.x >> 6] = ss;
  __syncthreads();
  float tot = wsum[0] + wsum[1] + wsum[2] + wsum[3];
  float norm = fmaxf(sqrtf(tot), 1e-15f);
  float scale = (norm > MAXNORM_) ? (MAXNORM_ / norm) : 1.0f;
  float xp = x * scale;
  float pnorm = fmaxf(fminf(norm, MAXNORM_), 1e-15f);
  float ratio = atanhf(pnorm) / pnorm;   // arg = clip(pnorm, ..., 1-eps): no-op here
  float y = ratio * xp;
  G[row * H_ + threadIdx.x] = fmaxf(y, 0.f) + 0.5f * __cosf(y + PHI_);
}

// ---------------------------------------------------------------------------
extern "C" void kernel_launch(void* const* d_in, const int* in_sizes, int n_in,
                              void* d_out, int out_size, void* d_ws, size_t ws_size,
                              hipStream_t stream) {
  const float* data = (const float*)d_in[0];
  const float* W1   = (const float*)d_in[1];
  const float* b1   = (const float*)d_in[2];
  const float* W2   = (const float*)d_in[3];
  const float* b2   = (const float*)d_in[4];

  float* g2  = (float*)d_out;                         // [B, N, H]
  float* adj = g2 + (size_t)B_ * N_ * H_;             // [B, N, N]

  float* ws   = (float*)d_ws;
  float* mean = ws;                    // BN_
  float* rd   = ws + BN_;              // BN_
  float* dinv = ws + 2 * BN_;          // BN_
  float* bufA = ws + 3 * BN_;          // B*N*H floats (~69 MB)

  // 1. stats
  stats_kernel<<<B_, 256, 0, stream>>>(data, mean, rd);
  // 2. adjacency (also output #2) straight into d_out
  corr_kernel<<<dim3(5, 5, B_), 256, 0, stream>>>(data, mean, rd, adj);
  // 3. D^-1/2
  dinv_kernel<<<BN_ / 4, 256, 0, stream>>>(adj, dinv);
  // 4. Y1 = adj @ W1            -> bufA
  gemm_aw_kernel<N_><<<dim3(4, 5, B_), 256, 0, stream>>>(adj, W1, bufA);
  // 5. X1 = L @ Y1 + b1         -> g2 region (scratch for now)
  gemm_lx_kernel<<<dim3(4, 5, B_), 256, 0, stream>>>(adj, dinv, bufA, b1, g2);
  // 6. g1 = act(fkernel(X1))    -> bufA
  actfk_kernel<<<BN_, 256, 0, stream>>>(g2, bufA);
  // 7. Y2 = g1 @ W2             -> g2 region (scratch)
  gemm_aw_kernel<H_><<<dim3(4, 5, B_), 256, 0, stream>>>(bufA, W2, g2);
  // 8. X2 = L @ Y2 + b2         -> bufA
  gemm_lx_kernel<<<dim3(4, 5, B_), 256, 0, stream>>>(adj, dinv, g2, b2, bufA);
  // 9. g2 = act(fkernel(X2))    -> final output
  actfk_kernel<<<BN_, 256, 0, stream>>>(bufA, g2);
}

// Round 4
// 551.091 us; speedup vs baseline: 2.4734x; 2.4734x over previous
//
#include <hip/hip_runtime.h>
#include <hip/hip_bf16.h>
#include <math.h>

#define B_ 256
#define T_ 240
#define N_ 264
#define H_ 256
#define BN_ (B_ * N_)
#define PHI_ 0.94247778f   // 3.1415926 * 0.3
#define MAXNORM_ 0.996f    // (1 - 4e-3)/sqrt(c), c=1

typedef short short8 __attribute__((ext_vector_type(8)));     // 8 bf16 (4 VGPRs) MFMA A/B frag
typedef float f32x4 __attribute__((ext_vector_type(4)));      // MFMA C/D frag
typedef unsigned short ushort4v __attribute__((ext_vector_type(4)));

__device__ inline unsigned short f2bf(float f) {
  __hip_bfloat16 h = __float2bfloat16(f);
  return *reinterpret_cast<unsigned short*>(&h);
}
__device__ inline float bf2f(unsigned short u) {
  unsigned int x = ((unsigned int)u) << 16;
  return __uint_as_float(x);
}

// ---------------------------------------------------------------------------
// Kernel 1: per-(b,n) mean and 1/std over T (single pass)
// ---------------------------------------------------------------------------
__global__ __launch_bounds__(256) void stats_kernel(
    const float* __restrict__ data, float* __restrict__ mean, float* __restrict__ rd) {
  int b = blockIdx.x;
  const float* db = data + (size_t)b * T_ * N_;
  for (int n = threadIdx.x; n < N_; n += blockDim.x) {
    float s = 0.f, ss = 0.f;
    for (int t = 0; t < T_; ++t) {
      float v = db[(size_t)t * N_ + n];
      s += v; ss += v * v;
    }
    float m = s / (float)T_;
    float var = ss - s * m;
    float d = sqrtf(fmaxf(var, 0.f));
    mean[b * N_ + n] = m;
    rd[b * N_ + n] = (d > 0.f) ? (1.f / d) : 0.f;   // nan_to_num semantics
  }
}

// ---------------------------------------------------------------------------
// Kernel 2: z[b][n][t] = bf16((data[b][t][n]-mean)*rd), [BN][256], t>=240 -> 0
// (rd folded here so corr = |z.z^T| directly). Transpose via LDS.
// ---------------------------------------------------------------------------
__global__ __launch_bounds__(256) void zT_kernel(
    const float* __restrict__ data, const float* __restrict__ mean,
    const float* __restrict__ rd, unsigned short* __restrict__ z) {
  int b = blockIdx.y;
  int n0 = blockIdx.x * 64;
  __shared__ unsigned short zl[64][242];   // stride 242 -> 121 words, gcd(121,32)=1
  int lane = threadIdx.x & 63, wv = threadIdx.x >> 6;
  int n = n0 + lane;
  float m = 0.f, r = 0.f;
  if (n < N_) { m = mean[b * N_ + n]; r = rd[b * N_ + n]; }
  for (int t = wv; t < T_; t += 4) {
    float v = (n < N_) ? data[((size_t)b * T_ + t) * N_ + n] : 0.f;
    zl[lane][t] = f2bf((v - m) * r);
  }
  __syncthreads();
  int tid = threadIdx.x;
  for (int rr = 0; rr < 64; ++rr) {
    int nn = n0 + rr;
    if (nn >= N_) break;
    unsigned short val = (tid < T_) ? zl[rr][tid] : (unsigned short)0;
    z[((size_t)b * N_ + nn) * 256 + tid] = val;
  }
}

// ---------------------------------------------------------------------------
// Kernel 3: WT[h][j] = bf16(W[j][h]), j-pad to Jpad with zeros
// ---------------------------------------------------------------------------
__global__ __launch_bounds__(256) void wtrans_kernel(
    const float* __restrict__ W, unsigned short* __restrict__ WT,
    int Jv, int Jpad) {
  int jt = blockIdx.x * 64, ht = blockIdx.y * 64;
  __shared__ float tile[64][65];
  int tid = threadIdx.x;
  for (int idx = tid; idx < 4096; idx += 256) {
    int jr = idx >> 6, hr = idx & 63;
    int j = jt + jr;
    tile[jr][hr] = (j < Jv) ? W[(size_t)j * H_ + ht + hr] : 0.f;
  }
  __syncthreads();
  for (int idx = tid; idx < 4096; idx += 256) {
    int hr = idx >> 6, jr = idx & 63;
    int j = jt + jr;
    if (j < Jpad) WT[(size_t)(ht + hr) * Jpad + j] = f2bf(tile[jr][hr]);
  }
}

// ---------------------------------------------------------------------------
// Kernel 4: dinv[b,i] = (sum_j adj[b,i,j] + 1)^-1/2
// ---------------------------------------------------------------------------
__global__ __launch_bounds__(256) void dinv_kernel(
    const float* __restrict__ adj, float* __restrict__ dinv) {
  int row  = blockIdx.x * 4 + (threadIdx.x >> 6);
  int lane = threadIdx.x & 63;
  const float* r = adj + (size_t)row * N_;
  float s = 0.f;
  for (int j = lane; j < N_; j += 64) s += r[j];
#pragma unroll
  for (int off = 32; off; off >>= 1) s += __shfl_down(s, off);
  if (lane == 0) dinv[row] = 1.f / sqrtf(s + 1.f);
}

// ---------------------------------------------------------------------------
// MFMA GEMM template: C[64 x 256] tile per block, 4 waves (1x4), wave 64x64,
// K-step 32, m97 proportions (16 MFMA : 8 ds_read_b128 per wave-step).
// A row-major [rows][K] bf16 (lda), B^T row-major [cols][K] bf16 (ldb).
// EPI 0: corr  -> adjF f32 [264][264] + adjB bf16 [264][288] (k-pad zeroed)
// EPI 1: aw    -> YT bf16 [256 cols][288]: YT[h][j] = dinv_j * acc  (pad 0)
// EPI 2: lx    -> g1 bf16 [264][256], fused bias + L-diag + project/logmap/act
// EPI 3: lx    -> g2 f32  [264][256], same epilogue
// ---------------------------------------------------------------------------
template<int EPI>
__global__ __launch_bounds__(256) void mfma_gemm_kernel(
    const unsigned short* __restrict__ A, int lda, long sA,
    const unsigned short* __restrict__ Bm, int ldb, long sB,
    int ksteps,
    float* __restrict__ outF, unsigned short* __restrict__ outB,
    const float* __restrict__ dinv, const float* __restrict__ bias) {
  int b = blockIdx.z;
  int i0 = blockIdx.y * 64;
  int n0 = blockIdx.x * 256;
  int tid = threadIdx.x;
  int w = tid >> 6, lane = tid & 63, g = lane >> 4, l4 = lane & 15;

  __shared__ short8 AsV[4 * 64];    // [kg][row]  : 4 KB
  __shared__ short8 BsV[4 * 256];   // [kg][ncol] : 16 KB

  const unsigned short* Ab = A + (size_t)b * sA;
  const unsigned short* Bb = Bm + (size_t)b * sB;

  f32x4 acc[4][4];
#pragma unroll
  for (int x = 0; x < 4; ++x)
#pragma unroll
    for (int y = 0; y < 4; ++y) acc[x][y] = (f32x4){0.f, 0.f, 0.f, 0.f};

  int arow = tid >> 2, akg = tid & 3;   // staging chunk coords (coalesced 64B/row)
  for (int ks = 0; ks < ksteps; ++ks) {
    int k0 = ks * 32;
    short8 av = *(const short8*)(Ab + (size_t)(i0 + arow) * lda + k0 + akg * 8);
    short8 bv[4];
#pragma unroll
    for (int it = 0; it < 4; ++it) {
      int nn = n0 + arow + it * 64;
      bv[it] = *(const short8*)(Bb + (size_t)nn * ldb + k0 + akg * 8);
    }
    __syncthreads();
    AsV[akg * 64 + arow] = av;
#pragma unroll
    for (int it = 0; it < 4; ++it) BsV[akg * 256 + arow + it * 64] = bv[it];
    __syncthreads();
    short8 af[4], bfr[4];
#pragma unroll
    for (int fr = 0; fr < 4; ++fr) af[fr] = AsV[g * 64 + fr * 16 + l4];
#pragma unroll
    for (int fc = 0; fc < 4; ++fc) bfr[fc] = BsV[g * 256 + w * 64 + fc * 16 + l4];
#pragma unroll
    for (int fr = 0; fr < 4; ++fr)
#pragma unroll
      for (int fc = 0; fc < 4; ++fc)
        acc[fr][fc] = __builtin_amdgcn_mfma_f32_16x16x32_bf16(af[fr], bfr[fc], acc[fr][fc], 0, 0, 0);
  }
  // C/D frag map (verified m89/m91): col = lane&15, row = (lane>>4)*4 + reg

  if constexpr (EPI == 0) {
#pragma unroll
    for (int fr = 0; fr < 4; ++fr) {
      int rb = i0 + fr * 16 + g * 4;
#pragma unroll
      for (int fc = 0; fc < 4; ++fc) {
        int j = n0 + w * 64 + fc * 16 + l4;
#pragma unroll
        for (int reg = 0; reg < 4; ++reg) {
          int i = rb + reg;
          float v = fabsf(acc[fr][fc][reg]);
          if (i < N_ && j < N_) outF[((size_t)b * N_ + i) * N_ + j] = v;
          if (i < N_ && j < 288) outB[((size_t)b * N_ + i) * 288 + j] = f2bf(j < N_ ? v : 0.f);
        }
      }
    }
  }

  if constexpr (EPI == 1) {
#pragma unroll
    for (int fr = 0; fr < 4; ++fr) {
      int rb = i0 + fr * 16 + g * 4;
      if (rb < 288) {
        float dv[4];
#pragma unroll
        for (int reg = 0; reg < 4; ++reg) {
          int j = rb + reg;
          dv[reg] = (j < N_) ? dinv[b * N_ + j] : 0.f;   // pad rows -> exact 0
        }
#pragma unroll
        for (int fc = 0; fc < 4; ++fc) {
          int col = w * 64 + fc * 16 + l4;
          ushort4v pk;
#pragma unroll
          for (int reg = 0; reg < 4; ++reg)
            pk[reg] = f2bf(dv[reg] * acc[fr][fc][reg]);
          *(ushort4v*)(outB + ((size_t)b * H_ + col) * 288 + rb) = pk;
        }
      }
    }
  }

  if constexpr (EPI >= 2) {
    __shared__ float rs[64][4];
    float ratio[4][4];
    // X = dinv_i * (acc + YT[col][i]) + bias[col]   (diag of L folded via YT)
#pragma unroll
    for (int fr = 0; fr < 4; ++fr) {
      int rb = i0 + fr * 16 + g * 4;
      float din[4];
#pragma unroll
      for (int reg = 0; reg < 4; ++reg) din[reg] = dinv[b * N_ + rb + reg];
#pragma unroll
      for (int fc = 0; fc < 4; ++fc) {
        int col = w * 64 + fc * 16 + l4;
        ushort4v dy = *(const ushort4v*)(Bb + (size_t)col * ldb + rb);
        float bias_v = bias[col];
#pragma unroll
        for (int reg = 0; reg < 4; ++reg) {
          float x = din[reg] * (acc[fr][fc][reg] + bf2f(dy[reg])) + bias_v;
          acc[fr][fc][reg] = x;
        }
      }
    }
    // per-row sum of x^2: in-lane over fc, shfl over the 16-lane col group,
    // LDS over the 4 waves
#pragma unroll
    for (int fr = 0; fr < 4; ++fr) {
#pragma unroll
      for (int reg = 0; reg < 4; ++reg) {
        float s = 0.f;
#pragma unroll
        for (int fc = 0; fc < 4; ++fc) { float x = acc[fr][fc][reg]; s += x * x; }
        s += __shfl_xor(s, 1); s += __shfl_xor(s, 2);
        s += __shfl_xor(s, 4); s += __shfl_xor(s, 8);
        if (l4 == 0) rs[fr * 16 + g * 4 + reg][w] = s;
      }
    }
    __syncthreads();
#pragma unroll
    for (int fr = 0; fr < 4; ++fr)
#pragma unroll
      for (int reg = 0; reg < 4; ++reg) {
        int r = fr * 16 + g * 4 + reg;
        float tot = rs[r][0] + rs[r][1] + rs[r][2] + rs[r][3];
        float norm = fmaxf(sqrtf(tot), 1e-15f);
        float scale = (norm > MAXNORM_) ? (MAXNORM_ / norm) : 1.0f;
        float pn = fmaxf(fminf(norm, MAXNORM_), 1e-15f);
        ratio[fr][reg] = atanhf(pn) / pn * scale;
      }
#pragma unroll
    for (int fr = 0; fr < 4; ++fr) {
      int rb = i0 + fr * 16 + g * 4;
#pragma unroll
      for (int fc = 0; fc < 4; ++fc) {
        int col = w * 64 + fc * 16 + l4;
#pragma unroll
        for (int reg = 0; reg < 4; ++reg) {
          int row = rb + reg;
          if (row < N_) {
            float y = ratio[fr][reg] * acc[fr][fc][reg];
            float o = fmaxf(y, 0.f) + 0.5f * __cosf(y + PHI_);
            if constexpr (EPI == 2) outB[((size_t)b * N_ + row) * H_ + col] = f2bf(o);
            else                    outF[((size_t)b * N_ + row) * H_ + col] = o;
          }
        }
      }
    }
  }
}

// ---------------------------------------------------------------------------
extern "C" void kernel_launch(void* const* d_in, const int* in_sizes, int n_in,
                              void* d_out, int out_size, void* d_ws, size_t ws_size,
                              hipStream_t stream) {
  const float* data = (const float*)d_in[0];
  const float* W1   = (const float*)d_in[1];
  const float* b1   = (const float*)d_in[2];
  const float* W2   = (const float*)d_in[3];
  const float* b2   = (const float*)d_in[4];

  float* g2   = (float*)d_out;                          // [B,N,H] f32
  float* adjF = g2 + (size_t)B_ * N_ * H_;              // [B,N,N] f32

  float* ws_f = (float*)d_ws;
  float* mean = ws_f;                                   // BN
  float* rd   = ws_f + BN_;                             // BN
  float* dinv = ws_f + 2 * BN_;                         // BN
  unsigned short* region1 = (unsigned short*)(ws_f + 3 * BN_);
  unsigned short* z    = region1;                       // [BN][256], dead after corr
  unsigned short* YT   = region1;                       // [B*256][288], reused layer2
  unsigned short* W1T  = region1 + (size_t)B_ * H_ * 288;   // [256][288]
  unsigned short* W2T  = W1T + (size_t)H_ * 288;            // [256][256]
  unsigned short* adjB = W2T + (size_t)H_ * H_;             // [B][264][288] (+~32KB tail slack assumed)
  unsigned short* g1bf = (unsigned short*)d_out;        // scratch inside g2 region

  stats_kernel<<<B_, 256, 0, stream>>>(data, mean, rd);
  zT_kernel<<<dim3(5, B_), 256, 0, stream>>>(data, mean, rd, z);
  wtrans_kernel<<<dim3(5, 4), 256, 0, stream>>>(W1, W1T, N_, 288);
  wtrans_kernel<<<dim3(4, 4), 256, 0, stream>>>(W2, W2T, H_, 256);
  // adj = |z z^T|  (also writes bf16 copy, k-padded)
  mfma_gemm_kernel<0><<<dim3(2, 5, B_), 256, 0, stream>>>(
      z, 256, (long)N_ * 256, z, 256, (long)N_ * 256, 8, adjF, adjB, nullptr, nullptr);
  dinv_kernel<<<BN_ / 4, 256, 0, stream>>>(adjF, dinv);
  // Y1T[h][j] = dinv_j * (adj @ W1)[j][h]
  mfma_gemm_kernel<1><<<dim3(1, 5, B_), 256, 0, stream>>>(
      adjB, 288, (long)N_ * 288, W1T, 288, 0L, 9, nullptr, YT, dinv, nullptr);
  // g1 = act(fkernel(dinv_i*(adj @ Y1T^T + diag) + b1))
  mfma_gemm_kernel<2><<<dim3(1, 5, B_), 256, 0, stream>>>(
      adjB, 288, (long)N_ * 288, YT, 288, (long)H_ * 288, 9, nullptr, g1bf, dinv, b1);
  // Y2T[h][j] = dinv_j * (g1 @ W2)[j][h]
  mfma_gemm_kernel<1><<<dim3(1, 5, B_), 256, 0, stream>>>(
      g1bf, 256, (long)N_ * 256, W2T, 256, 0L, 8, nullptr, YT, dinv, nullptr);
  // g2 = act(fkernel(...)) -> final f32 output
  mfma_gemm_kernel<3><<<dim3(1, 5, B_), 256, 0, stream>>>(
      adjB, 288, (long)N_ * 288, YT, 288, (long)H_ * 288, 9, g2, nullptr, dinv, b2);
}